// Round 11
// baseline (3031.164 us; speedup 1.0000x reference)
//
#include <hip/hip_runtime.h>
#include <hip/hip_bf16.h>

// AUGRU dynamic RNN: B=1024, T=512, D=128.
// Round-11: TLP=4 two-group blocks. 32 blocks x 1024 threads (16 waves);
// waves 0-7 process batch group A (16 rows), waves 8-15 group B (next 16).
// Each SIMD hosts 2 A-waves + 2 B-waves -> 4 waves/SIMD latency hiding.
// Each wave's stream is byte-identical to R9's (525.8us best): R5 cross-step
// x-partials, R9 column-aligned gates + register-resident h, cvt_pk_bf16,
// folded biases, lgkm-only barriers, 2 barriers/step. R10 proved the kernel
// is latency-stall-bound hidden by TLP (TLP=1 cost +70% with identical pipe
// work); R9's ~29% non-busy residual is exposed stall -> absorb with TLP=4.
// Groups phase-aligned on one shared barrier. Per-group LDS (35.8KB).
// VGPR must stay <=128 (4 waves/SIMD): R9 used 112, per-wave state unchanged.

#define Bn 1024
#define Tn 512
#define Dn 128

typedef __attribute__((ext_vector_type(8))) short short8;   // 8 bf16 (4 VGPR)
typedef __attribute__((ext_vector_type(4))) float f32x4;

#define BS 136   // bf16 LDS row stride (shorts): 272 B = 17*16B

#define NL2E  (-1.4426950408889634f)   // -log2(e)
#define N2L2E (-2.8853900817779268f)   // -2*log2(e)

__device__ __forceinline__ short f2bf(float f) {            // cold paths only
    __hip_bfloat16 h = __float2bfloat16(f);   // RNE
    return __builtin_bit_cast(short, h);
}
__device__ __forceinline__ unsigned cvt_pk_bf16(float a, float b) {
    unsigned r;
    asm("v_cvt_pk_bf16_f32 %0, %1, %2" : "=v"(r) : "v"(a), "v"(b));
    return r;
}
// LDS-only barrier: order LDS ops across waves WITHOUT draining vmcnt.
__device__ __forceinline__ void barrier_lds() {
    __builtin_amdgcn_sched_barrier(0);
    asm volatile("s_waitcnt lgkmcnt(0)" ::: "memory");
    __builtin_amdgcn_s_barrier();
    __builtin_amdgcn_sched_barrier(0);
}

#define MFMA_(a, b, c) __builtin_amdgcn_mfma_f32_16x16x32_bf16((a), (b), (c), 0, 0, 0)

__launch_bounds__(1024, 4)
__global__ void augru_kernel(const float* __restrict__ X,    // [B,T,D]
                             const float* __restrict__ ATT,  // [B,T,1]
                             const float* __restrict__ GK,   // [256,256]
                             const float* __restrict__ GB,   // [256]
                             const float* __restrict__ CK,   // [256,128]
                             const float* __restrict__ CB,   // [128]
                             const int*   __restrict__ SL,   // [B,1]
                             float* __restrict__ OUT) {      // [B,T,D]
    __shared__ short hb [2][16 * BS];      // h bf16 mirror, per group
    __shared__ short rhb[2][16 * BS];      // r*h bf16, per group
    __shared__ short xb [2][2][16 * BS];   // [group][slot]; slot s&1 = x(s)
    __shared__ float abuf[2][2][16];
    __shared__ int   lenbuf[2][16];

    const int tid  = threadIdx.x;
    const int g    = tid >> 9;          // group 0/1 (waves 0-7 / 8-15)
    const int g512 = tid & 511;         // thread id within group
    const int wv   = (tid >> 6) & 7;    // column-wave within group (0..7)
    const int lane = tid & 63;
    const int lm   = lane & 15;
    const int q    = lane >> 4;
    const int b0   = blockIdx.x * 32 + 16 * g;
    const int ccol = 16 * wv + lm;      // wave's owned column

    // ---------- preload weight B-frags (B[k][n]: n=lane&15, k=q*8+j) ----------
    // gate group 0 -> col ccol (r); gate group 1 -> col 128+ccol (u).
    short8 fgx0[4], fgx1[4], fgh0[4], fgh1[4], fcx[4], fch[4];
#pragma unroll
    for (int ks = 0; ks < 4; ++ks) {
        short8 v0, v1, v2, v3, v4, v5;
#pragma unroll
        for (int j = 0; j < 8; ++j) {
            const int k = ks * 32 + q * 8 + j;
            v0[j] = f2bf(GK[k * 256 + ccol]);               // x-part, r col
            v1[j] = f2bf(GK[k * 256 + 128 + ccol]);         // x-part, u col
            v2[j] = f2bf(GK[(128 + k) * 256 + ccol]);       // h-part, r col
            v3[j] = f2bf(GK[(128 + k) * 256 + 128 + ccol]); // h-part, u col
            v4[j] = f2bf(CK[k * 128 + ccol]);               // cand x-part
            v5[j] = f2bf(CK[(128 + k) * 128 + ccol]);       // cand rh-part
        }
        fgx0[ks] = v0; fgx1[ks] = v1; fgh0[ks] = v2; fgh1[ks] = v3;
        fcx[ks] = v4;  fch[ks] = v5;
    }
    const float pb0 = GB[ccol]       * NL2E;
    const float pb1 = GB[128 + ccol] * NL2E;
    const float cbp = CB[ccol]       * N2L2E;

    // ---------- init LDS (each group's threads init its own arrays) ----------
    for (int i = g512; i < 16 * BS; i += 512) hb[g][i] = 0;
    if (g512 < 16) {
        lenbuf[g][g512]  = SL[b0 + g512];
        abuf[g][0][g512] = ATT[(size_t)(b0 + g512) * Tn];
    }
    const int prow = g512 >> 5;           // x staging: row 0..15
    const int pcol = (g512 & 31) * 4;     // 4 consecutive floats
    {   // stage x(0) into xb[g][0]
        float4 v = *(const float4*)(X + ((size_t)(b0 + prow) * Tn + 0) * Dn + pcol);
        uint2 pp; pp.x = cvt_pk_bf16(v.x, v.y); pp.y = cvt_pk_bf16(v.z, v.w);
        *(uint2*)&xb[g][0][prow * BS + pcol] = pp;
    }
    __syncthreads();

    int len_i[4];
    float h_reg[4] = {0.f, 0.f, 0.f, 0.f};   // master h: rows q*4+i, col ccol
#pragma unroll
    for (int i = 0; i < 4; ++i) len_i[i] = lenbuf[g][q * 4 + i];

    // ---------- prologue: x-partials for t=0; stage x(1) ----------
    f32x4 gxA0 = {0,0,0,0}, gxA1 = {0,0,0,0}, cxA = {0,0,0,0};
    f32x4 gxB0, gxB1, cxB;
    {
        short8 ax0[4];
#pragma unroll
        for (int ks = 0; ks < 4; ++ks)
            ax0[ks] = *(const short8*)&xb[g][0][lm * BS + ks * 32 + q * 8];
#pragma unroll
        for (int ks = 0; ks < 4; ++ks) {
            gxA0 = MFMA_(ax0[ks], fgx0[ks], gxA0);
            gxA1 = MFMA_(ax0[ks], fgx1[ks], gxA1);
            cxA  = MFMA_(ax0[ks], fcx[ks],  cxA);
        }
        float4 v = *(const float4*)(X + ((size_t)(b0 + prow) * Tn + 1) * Dn + pcol);
        uint2 pp; pp.x = cvt_pk_bf16(v.x, v.y); pp.y = cvt_pk_bf16(v.z, v.w);
        *(uint2*)&xb[g][1][prow * BS + pcol] = pp;
    }
    __syncthreads();

#define STEP_BODY(t, GIN0, GIN1, CIN, GOUT0, GOUT1, COUT)                         \
    {                                                                             \
        const int cur = (t) & 1, nxt = cur ^ 1;                                   \
        const int tp1 = ((t) + 1 < Tn) ? (t) + 1 : Tn - 1;                        \
        const int tp2 = ((t) + 2 < Tn) ? (t) + 2 : Tn - 1;                        \
        float4 xpre = *(const float4*)(X + ((size_t)(b0 + prow) * Tn + tp2) * Dn + pcol); \
        float  apre = (g512 < 16) ? ATT[(size_t)(b0 + g512) * Tn + tp1] : 0.0f;   \
        /* A-frags: h(t) from hb, x(t+1) from xb[g][nxt] */                       \
        short8 axn[4], ah[4];                                                     \
        _Pragma("unroll")                                                         \
        for (int ks = 0; ks < 4; ++ks) {                                          \
            axn[ks] = *(const short8*)&xb[g][nxt][lm * BS + ks * 32 + q * 8];     \
            ah[ks]  = *(const short8*)&hb[g][lm * BS + ks * 32 + q * 8];          \
        }                                                                         \
        /* P1: gate = saved x-partial + h-part (4-deep); next x-partials float */ \
        f32x4 g0 = GIN0, g1 = GIN1;                                               \
        f32x4 n0 = {0,0,0,0}, n1 = {0,0,0,0}, n2 = {0,0,0,0};                     \
        _Pragma("unroll")                                                         \
        for (int ks = 0; ks < 4; ++ks) {                                          \
            g0 = MFMA_(ah[ks], fgh0[ks], g0);                                     \
            g1 = MFMA_(ah[ks], fgh1[ks], g1);                                     \
        }                                                                         \
        _Pragma("unroll")                                                         \
        for (int ks = 0; ks < 4; ++ks) {                                          \
            n0 = MFMA_(axn[ks], fgx0[ks], n0);                                    \
            n1 = MFMA_(axn[ks], fgx1[ks], n1);                                    \
            n2 = MFMA_(axn[ks], fcx[ks],  n2);                                    \
        }                                                                         \
        /* activations: wave-uniform; r,u for col ccol in the owning lane */      \
        float am[4], up[4], rhv[4];                                               \
        _Pragma("unroll")                                                         \
        for (int i = 0; i < 4; ++i) am[i] = 1.0f - abuf[g][cur][q * 4 + i];       \
        _Pragma("unroll")                                                         \
        for (int i = 0; i < 4; ++i) {                                             \
            const float e0 = __builtin_amdgcn_exp2f(fmaf(g0[i], NL2E, pb0));      \
            rhv[i] = __builtin_amdgcn_rcpf(1.0f + e0) * h_reg[i];                 \
            const float e1 = __builtin_amdgcn_exp2f(fmaf(g1[i], NL2E, pb1));      \
            up[i] = am[i] * __builtin_amdgcn_rcpf(1.0f + e1);                     \
        }                                                                         \
        {                                                                         \
            const unsigned pA_ = cvt_pk_bf16(rhv[0], rhv[1]);                     \
            const unsigned pB_ = cvt_pk_bf16(rhv[2], rhv[3]);                     \
            rhb[g][(q * 4 + 0) * BS + ccol] = (short)pA_;                         \
            rhb[g][(q * 4 + 1) * BS + ccol] = (short)(pA_ >> 16);                 \
            rhb[g][(q * 4 + 2) * BS + ccol] = (short)pB_;                         \
            rhb[g][(q * 4 + 3) * BS + ccol] = (short)(pB_ >> 16);                 \
        }                                                                         \
        barrier_lds();                                                            \
        /* P2: cand = saved x-partial + rh-part (4-deep) */                       \
        f32x4 cc = CIN;                                                           \
        _Pragma("unroll")                                                         \
        for (int ks = 0; ks < 4; ++ks) {                                          \
            short8 arh = *(const short8*)&rhb[g][lm * BS + ks * 32 + q * 8];      \
            cc = MFMA_(arh, fch[ks], cc);                                         \
        }                                                                         \
        /* h update + output (all state register-resident) */                     \
        float hxv[4];                                                             \
        _Pragma("unroll")                                                         \
        for (int i = 0; i < 4; ++i) {                                             \
            const int row = q * 4 + i;                                            \
            const float e  = __builtin_amdgcn_exp2f(fmaf(cc[i], N2L2E, cbp));     \
            const float cv = fmaf(2.0f, __builtin_amdgcn_rcpf(1.0f + e), -1.0f);  \
            const float hn = fmaf(up[i], h_reg[i] - cv, cv);                      \
            const bool valid = ((t) < len_i[i]);                                  \
            const float hnext = valid ? hn : h_reg[i];                            \
            OUT[((size_t)(b0 + row) * Tn + (t)) * Dn + ccol] = valid ? hn : 0.0f; \
            h_reg[i] = hnext;                                                     \
            hxv[i] = hnext;                                                       \
        }                                                                         \
        {                                                                         \
            const unsigned pA_ = cvt_pk_bf16(hxv[0], hxv[1]);                     \
            const unsigned pB_ = cvt_pk_bf16(hxv[2], hxv[3]);                     \
            hb[g][(q * 4 + 0) * BS + ccol] = (short)pA_;                          \
            hb[g][(q * 4 + 1) * BS + ccol] = (short)(pA_ >> 16);                  \
            hb[g][(q * 4 + 2) * BS + ccol] = (short)pB_;                          \
            hb[g][(q * 4 + 3) * BS + ccol] = (short)(pB_ >> 16);                  \
        }                                                                         \
        /* stage x(t+2) into xb[g][cur]; a(t+1) into abuf[g][nxt] */              \
        {                                                                         \
            uint2 pp_;                                                            \
            pp_.x = cvt_pk_bf16(xpre.x, xpre.y);                                  \
            pp_.y = cvt_pk_bf16(xpre.z, xpre.w);                                  \
            *(uint2*)&xb[g][cur][prow * BS + pcol] = pp_;                         \
            if (g512 < 16) abuf[g][nxt][g512] = apre;                             \
        }                                                                         \
        barrier_lds();                                                            \
        GOUT0 = n0; GOUT1 = n1; COUT = n2;                                        \
    }

    // ---------- time loop (unrolled x2: static A/B partial-sum sets) ----------
    for (int t = 0; t < Tn; t += 2) {
        STEP_BODY(t,     gxA0, gxA1, cxA, gxB0, gxB1, cxB)
        STEP_BODY(t + 1, gxB0, gxB1, cxB, gxA0, gxA1, cxA)
    }
#undef STEP_BODY
}

extern "C" void kernel_launch(void* const* d_in, const int* in_sizes, int n_in,
                              void* d_out, int out_size, void* d_ws, size_t ws_size,
                              hipStream_t stream) {
    (void)in_sizes; (void)n_in; (void)d_ws; (void)ws_size; (void)out_size;
    const float* X   = (const float*)d_in[0];
    const float* ATT = (const float*)d_in[1];
    const float* GK  = (const float*)d_in[2];
    const float* GB  = (const float*)d_in[3];
    const float* CK  = (const float*)d_in[4];
    const float* CB  = (const float*)d_in[5];
    const int*   SL  = (const int*)d_in[6];
    float* OUT = (float*)d_out;

    augru_kernel<<<dim3(Bn / 32), dim3(1024), 0, stream>>>(X, ATT, GK, GB, CK, CB, SL, OUT);
}

// Round 12
// 536.027 us; speedup vs baseline: 5.6549x; 5.6549x over previous
//
#include <hip/hip_runtime.h>
#include <hip/hip_bf16.h>

// AUGRU dynamic RNN: B=1024, T=512, D=128.
// 64 blocks x 512 threads (8 waves, TLP=2/SIMD); block owns 16 batch rows.
// Base = R9 (525.8us). Round-12 change: OPERAND-SWAPPED MFMA (transposed
// output ownership). gfx950 MFMA A- and B-fragment lane layouts are
// symmetric, so mfma(W,Data) reuses the same registers as mfma(Data,W) and
// produces D^T: lane (q,lm) owns batch row lm and FOUR CONSECUTIVE output
// cols 16w+4q..+4. This converts:
//   * rhb/hb LDS writes: 4 scattered ds_write_b16 -> 1 ds_write_b64 each
//     (write-side bank conflicts were the measured 384 cyc/step)
//   * OUT: 4 scattered dwords -> 1 global_store_dwordx4
//   * (1-a)/len/mask: per-lane scalar instead of 4 per-row values
// LDS b128 reads, weight-frag registers, math, barriers: identical to R9.
// Ledger: LDS pipe ~1940 of 2465 cyc/CU-step at R9 (reads 1152 minimal,
// writes ~400, conflicts 384). This attacks writes+conflicts.

#define Bn 1024
#define Tn 512
#define Dn 128

typedef __attribute__((ext_vector_type(8))) short short8;   // 8 bf16 (4 VGPR)
typedef __attribute__((ext_vector_type(4))) float f32x4;

#define BS 136   // bf16 LDS row stride (shorts): 272 B = 17*16B

#define NL2E  (-1.4426950408889634f)   // -log2(e)
#define N2L2E (-2.8853900817779268f)   // -2*log2(e)

__device__ __forceinline__ short f2bf(float f) {            // cold paths only
    __hip_bfloat16 h = __float2bfloat16(f);   // RNE
    return __builtin_bit_cast(short, h);
}
__device__ __forceinline__ unsigned cvt_pk_bf16(float a, float b) {
    unsigned r;
    asm("v_cvt_pk_bf16_f32 %0, %1, %2" : "=v"(r) : "v"(a), "v"(b));
    return r;
}
// LDS-only barrier: order LDS ops across waves WITHOUT draining vmcnt.
__device__ __forceinline__ void barrier_lds() {
    __builtin_amdgcn_sched_barrier(0);
    asm volatile("s_waitcnt lgkmcnt(0)" ::: "memory");
    __builtin_amdgcn_s_barrier();
    __builtin_amdgcn_sched_barrier(0);
}

#define MFMA_(a, b, c) __builtin_amdgcn_mfma_f32_16x16x32_bf16((a), (b), (c), 0, 0, 0)

__launch_bounds__(512, 1)
__global__ void augru_kernel(const float* __restrict__ X,    // [B,T,D]
                             const float* __restrict__ ATT,  // [B,T,1]
                             const float* __restrict__ GK,   // [256,256]
                             const float* __restrict__ GB,   // [256]
                             const float* __restrict__ CK,   // [256,128]
                             const float* __restrict__ CB,   // [128]
                             const int*   __restrict__ SL,   // [B,1]
                             float* __restrict__ OUT) {      // [B,T,D]
    __shared__ short hb [16 * BS];      // h  (bf16 mirror, B-frag source)
    __shared__ short rhb[16 * BS];      // r*h (bf16, B-frag source)
    __shared__ short xb [2][16 * BS];   // x tile; slot s&1 holds x(s)
    __shared__ float abuf[2][16];
    __shared__ int   lenbuf[16];

    const int tid  = threadIdx.x;
    const int wid  = tid >> 6;          // 0..7
    const int lane = tid & 63;
    const int lm   = lane & 15;
    const int q    = lane >> 4;
    const int b0   = blockIdx.x * 16;
    const int cb   = 16 * wid;          // wave's col-set base
    const int ccol = cb + lm;           // preload addressing (frag content)
    const int c0   = cb + 4 * q;        // lane's first owned output col
    // After swap: lane (q,lm) owns batch row lm, cols c0..c0+3.

    // ---------- preload weight frags (same per-lane content as R9) ----------
    // Used as the A-operand: A[m=lm][k=q*8+j] = W[k][cb+lm].
    short8 fgx0[4], fgx1[4], fgh0[4], fgh1[4], fcx[4], fch[4];
#pragma unroll
    for (int ks = 0; ks < 4; ++ks) {
        short8 v0, v1, v2, v3, v4, v5;
#pragma unroll
        for (int j = 0; j < 8; ++j) {
            const int k = ks * 32 + q * 8 + j;
            v0[j] = f2bf(GK[k * 256 + ccol]);               // x-part, r col
            v1[j] = f2bf(GK[k * 256 + 128 + ccol]);         // x-part, u col
            v2[j] = f2bf(GK[(128 + k) * 256 + ccol]);       // h-part, r col
            v3[j] = f2bf(GK[(128 + k) * 256 + 128 + ccol]); // h-part, u col
            v4[j] = f2bf(CK[k * 128 + ccol]);               // cand x-part
            v5[j] = f2bf(CK[(128 + k) * 128 + ccol]);       // cand rh-part
        }
        fgx0[ks] = v0; fgx1[ks] = v1; fgh0[ks] = v2; fgh1[ks] = v3;
        fcx[ks] = v4;  fch[ks] = v5;
    }
    // biases: per owned output col (4 per lane), pre-folded into exp2 arg
    float pb0[4], pb1[4], cbp[4];
#pragma unroll
    for (int i = 0; i < 4; ++i) {
        pb0[i] = GB[c0 + i]       * NL2E;
        pb1[i] = GB[128 + c0 + i] * NL2E;
        cbp[i] = CB[c0 + i]       * N2L2E;
    }

    // ---------- init LDS ----------
    for (int i = tid; i < 16 * BS; i += 512) hb[i] = 0;
    if (tid < 16) {
        lenbuf[tid]  = SL[b0 + tid];
        abuf[0][tid] = ATT[(size_t)(b0 + tid) * Tn];
    }
    const int prow = tid >> 5;            // x staging: row 0..15
    const int pcol = (tid & 31) * 4;      // 4 consecutive floats
    {   // stage x(0) into xb[0]
        float4 v = *(const float4*)(X + ((size_t)(b0 + prow) * Tn + 0) * Dn + pcol);
        uint2 pp; pp.x = cvt_pk_bf16(v.x, v.y); pp.y = cvt_pk_bf16(v.z, v.w);
        *(uint2*)&xb[0][prow * BS + pcol] = pp;
    }
    __syncthreads();

    const int lenr = lenbuf[lm];             // this lane's batch-row length
    float h_reg[4] = {0.f, 0.f, 0.f, 0.f};   // h[batch lm][c0+i]

    // ---------- prologue: x-partials for t=0; stage x(1) ----------
    f32x4 gxA0 = {0,0,0,0}, gxA1 = {0,0,0,0}, cxA = {0,0,0,0};
    f32x4 gxB0, gxB1, cxB;
    {
        short8 ax0[4];
#pragma unroll
        for (int ks = 0; ks < 4; ++ks)
            ax0[ks] = *(const short8*)&xb[0][lm * BS + ks * 32 + q * 8];
#pragma unroll
        for (int ks = 0; ks < 4; ++ks) {
            gxA0 = MFMA_(fgx0[ks], ax0[ks], gxA0);   // swapped operands
            gxA1 = MFMA_(fgx1[ks], ax0[ks], gxA1);
            cxA  = MFMA_(fcx[ks],  ax0[ks], cxA);
        }
        float4 v = *(const float4*)(X + ((size_t)(b0 + prow) * Tn + 1) * Dn + pcol);
        uint2 pp; pp.x = cvt_pk_bf16(v.x, v.y); pp.y = cvt_pk_bf16(v.z, v.w);
        *(uint2*)&xb[1][prow * BS + pcol] = pp;
    }
    __syncthreads();

#define STEP_BODY(t, GIN0, GIN1, CIN, GOUT0, GOUT1, COUT)                         \
    {                                                                             \
        const int cur = (t) & 1, nxt = cur ^ 1;                                   \
        const int tp1 = ((t) + 1 < Tn) ? (t) + 1 : Tn - 1;                        \
        const int tp2 = ((t) + 2 < Tn) ? (t) + 2 : Tn - 1;                        \
        float4 xpre = *(const float4*)(X + ((size_t)(b0 + prow) * Tn + tp2) * Dn + pcol); \
        float  apre = (tid < 16) ? ATT[(size_t)(b0 + tid) * Tn + tp1] : 0.0f;     \
        /* data frags (as B-operands): identical b128 reads to R9 */              \
        short8 axn[4], ah[4];                                                     \
        _Pragma("unroll")                                                         \
        for (int ks = 0; ks < 4; ++ks) {                                          \
            axn[ks] = *(const short8*)&xb[nxt][lm * BS + ks * 32 + q * 8];        \
            ah[ks]  = *(const short8*)&hb[lm * BS + ks * 32 + q * 8];             \
        }                                                                         \
        /* P1: gate = saved x-partial + h-part; next x-partials float free */     \
        f32x4 g0 = GIN0, g1 = GIN1;                                               \
        f32x4 n0 = {0,0,0,0}, n1 = {0,0,0,0}, n2 = {0,0,0,0};                     \
        _Pragma("unroll")                                                         \
        for (int ks = 0; ks < 4; ++ks) {                                          \
            g0 = MFMA_(fgh0[ks], ah[ks], g0);                                     \
            g1 = MFMA_(fgh1[ks], ah[ks], g1);                                     \
        }                                                                         \
        _Pragma("unroll")                                                         \
        for (int ks = 0; ks < 4; ++ks) {                                          \
            n0 = MFMA_(fgx0[ks], axn[ks], n0);                                    \
            n1 = MFMA_(fgx1[ks], axn[ks], n1);                                    \
            n2 = MFMA_(fcx[ks],  axn[ks], n2);                                    \
        }                                                                         \
        /* activations: lane owns batch lm, cols c0..c0+3 (all in-register) */    \
        const float am_ = 1.0f - abuf[cur][lm];                                   \
        float up[4], rhv[4];                                                      \
        _Pragma("unroll")                                                         \
        for (int i = 0; i < 4; ++i) {                                             \
            const float e0 = __builtin_amdgcn_exp2f(fmaf(g0[i], NL2E, pb0[i]));   \
            rhv[i] = __builtin_amdgcn_rcpf(1.0f + e0) * h_reg[i];                 \
            const float e1 = __builtin_amdgcn_exp2f(fmaf(g1[i], NL2E, pb1[i]));   \
            up[i] = am_ * __builtin_amdgcn_rcpf(1.0f + e1);                       \
        }                                                                         \
        {   /* one aligned b64 write: rhb[lm][c0..c0+3] */                        \
            uint2 rp;                                                             \
            rp.x = cvt_pk_bf16(rhv[0], rhv[1]);                                   \
            rp.y = cvt_pk_bf16(rhv[2], rhv[3]);                                   \
            *(uint2*)&rhb[lm * BS + c0] = rp;                                     \
        }                                                                         \
        barrier_lds();                                                            \
        /* P2: cand = saved x-partial + rh-part */                                \
        f32x4 cc = CIN;                                                           \
        _Pragma("unroll")                                                         \
        for (int ks = 0; ks < 4; ++ks) {                                          \
            short8 arh = *(const short8*)&rhb[lm * BS + ks * 32 + q * 8];         \
            cc = MFMA_(fch[ks], arh, cc);                                         \
        }                                                                         \
        /* h update + output: per-lane scalar mask, vector store */               \
        const bool valid = ((t) < lenr);                                          \
        f32x4 outv;                                                               \
        _Pragma("unroll")                                                         \
        for (int i = 0; i < 4; ++i) {                                             \
            const float e  = __builtin_amdgcn_exp2f(fmaf(cc[i], N2L2E, cbp[i]));  \
            const float cv = fmaf(2.0f, __builtin_amdgcn_rcpf(1.0f + e), -1.0f);  \
            const float hn = fmaf(up[i], h_reg[i] - cv, cv);                      \
            h_reg[i] = valid ? hn : h_reg[i];                                     \
            outv[i]  = valid ? hn : 0.0f;                                         \
        }                                                                         \
        *(f32x4*)(OUT + ((size_t)(b0 + lm) * Tn + (t)) * Dn + c0) = outv;         \
        {   /* one aligned b64 write: hb[lm][c0..c0+3] */                         \
            uint2 hp;                                                             \
            hp.x = cvt_pk_bf16(h_reg[0], h_reg[1]);                               \
            hp.y = cvt_pk_bf16(h_reg[2], h_reg[3]);                               \
            *(uint2*)&hb[lm * BS + c0] = hp;                                      \
        }                                                                         \
        /* stage x(t+2) into xb[cur]; a(t+1) into abuf[nxt] */                    \
        {                                                                         \
            uint2 pp_;                                                            \
            pp_.x = cvt_pk_bf16(xpre.x, xpre.y);                                  \
            pp_.y = cvt_pk_bf16(xpre.z, xpre.w);                                  \
            *(uint2*)&xb[cur][prow * BS + pcol] = pp_;                            \
            if (tid < 16) abuf[nxt][tid] = apre;                                  \
        }                                                                         \
        barrier_lds();                                                            \
        GOUT0 = n0; GOUT1 = n1; COUT = n2;                                        \
    }

    // ---------- time loop (unrolled x2: static A/B partial-sum sets) ----------
    for (int t = 0; t < Tn; t += 2) {
        STEP_BODY(t,     gxA0, gxA1, cxA, gxB0, gxB1, cxB)
        STEP_BODY(t + 1, gxB0, gxB1, cxB, gxA0, gxA1, cxA)
    }
#undef STEP_BODY
}

extern "C" void kernel_launch(void* const* d_in, const int* in_sizes, int n_in,
                              void* d_out, int out_size, void* d_ws, size_t ws_size,
                              hipStream_t stream) {
    (void)in_sizes; (void)n_in; (void)d_ws; (void)ws_size; (void)out_size;
    const float* X   = (const float*)d_in[0];
    const float* ATT = (const float*)d_in[1];
    const float* GK  = (const float*)d_in[2];
    const float* GB  = (const float*)d_in[3];
    const float* CK  = (const float*)d_in[4];
    const float* CB  = (const float*)d_in[5];
    const int*   SL  = (const int*)d_in[6];
    float* OUT = (float*)d_out;

    augru_kernel<<<dim3(Bn / 16), dim3(512), 0, stream>>>(X, ATT, GK, GB, CK, CB, SL, OUT);
}